// Round 3
// baseline (48.045 us; speedup 1.0000x reference)
//
#include <hip/hip_runtime.h>
#include <type_traits>

typedef __attribute__((ext_vector_type(4))) float f32x4;
typedef __attribute__((ext_vector_type(8))) short s16x8;

__device__ __forceinline__ unsigned short f2bf(float f) {
    unsigned int u = __builtin_bit_cast(unsigned int, f);
    u += 0x7fffu + ((u >> 16) & 1u);           // round-to-nearest-even
    return (unsigned short)(u >> 16);
}

__device__ __forceinline__ void gload_lds16(const void* g, void* l) {
    __builtin_amdgcn_global_load_lds(
        (const __attribute__((address_space(1))) void*)g,
        (__attribute__((address_space(3))) void*)l, 16, 0, 0);
}

// ---------------------------------------------------------------------------
// LDS tile layout (bf16, 64 k-elems = 128 B per row):
//   byte(row, chunk) = row*128 + ((chunk ^ (row&7)) << 4)
// ---------------------------------------------------------------------------

// bf16 source staged via global_load_lds: linear LDS dest, pre-swizzled source.
template<int ROWS>
__device__ __forceinline__ void stage_lds(const unsigned short* __restrict__ src,
                                          int ld, int row0, int k0, int maxRowExcl,
                                          char* lds, int wid, int lane) {
    const int subrow = lane >> 3;            // 0..7
    const int gchunk = (lane & 7) ^ subrow;  // inverse swizzle on source
    #pragma unroll
    for (int p = 0; p < (ROWS + 31) / 32; ++p) {
        const int r0 = (p * 4 + wid) * 8;    // 8 rows / wave-call
        int gr = row0 + r0 + subrow;
        if (gr >= maxRowExcl) gr = maxRowExcl - 1;
        const char* g = (const char*)(src + (size_t)gr * ld + k0) + gchunk * 16;
        gload_lds16(g, lds + r0 * 128);      // wave-uniform base + lane*16
    }
}

// f32 source, T14 split: load -> regs (early), cvt+ds_write (late).
template<int ROWS>
__device__ __forceinline__ void stageB_load(const float* __restrict__ src, int ld,
                                            int row0, int k0, int maxRowExcl,
                                            f32x4 (&regs)[ROWS / 16], int tid) {
    const int r_in = tid >> 4;
    const int c4   = tid & 15;
    #pragma unroll
    for (int p = 0; p < ROWS / 16; ++p) {
        int gr = row0 + p * 16 + r_in;
        if (gr >= maxRowExcl) gr = maxRowExcl - 1;
        regs[p] = *reinterpret_cast<const f32x4*>(src + (size_t)gr * ld + k0 + c4 * 4);
    }
}

template<int ROWS>
__device__ __forceinline__ void stageB_write(const f32x4 (&regs)[ROWS / 16],
                                             char* lds, int tid) {
    const int r_in = tid >> 4;
    const int c4   = tid & 15;
    #pragma unroll
    for (int p = 0; p < ROWS / 16; ++p) {
        const int row = p * 16 + r_in;
        const unsigned int lo = (unsigned)f2bf(regs[p].x) | ((unsigned)f2bf(regs[p].y) << 16);
        const unsigned int hi = (unsigned)f2bf(regs[p].z) | ((unsigned)f2bf(regs[p].w) << 16);
        const int chunk = c4 >> 1;
        const int byte = row * 128 + ((chunk ^ (row & 7)) << 4) + (c4 & 1) * 8;
        *reinterpret_cast<uint2*>(lds + byte) = make_uint2(lo, hi);
    }
}

// One BK=64 step: fragment reads + MFMA.
template<int MF, int NF>
__device__ __forceinline__ void compute_step(const char* As, const char* Bs,
                                             int arow_base, int brow_base,
                                             int lr, int lg, f32x4 (&acc)[MF][NF]) {
    #pragma unroll
    for (int kk = 0; kk < 2; ++kk) {
        s16x8 af[MF], bfr[NF];
        const int chunk = kk * 4 + lg;
        #pragma unroll
        for (int f = 0; f < MF; ++f) {
            const int row = arow_base + f * 16 + lr;
            af[f] = *reinterpret_cast<const s16x8*>(As + row * 128 + ((chunk ^ (row & 7)) << 4));
        }
        #pragma unroll
        for (int f = 0; f < NF; ++f) {
            const int row = brow_base + f * 16 + lr;
            bfr[f] = *reinterpret_cast<const s16x8*>(Bs + row * 128 + ((chunk ^ (row & 7)) << 4));
        }
        #pragma unroll
        for (int mi = 0; mi < MF; ++mi)
            #pragma unroll
            for (int ni = 0; ni < NF; ++ni)
                acc[mi][ni] = __builtin_amdgcn_mfma_f32_16x16x32_bf16(
                    af[mi], bfr[ni], acc[mi][ni], 0, 0, 0);
    }
}

// Epilogue: C/D layout col = lane&15, row = (lane>>4)*4 + reg   [m89]
template<int MF, int NF, typename CT>
__device__ __forceinline__ void store_c(CT* __restrict__ C, int ldc, int N,
                                        int m0, int n0, int arow_base, int brow_base,
                                        int lr, int lg, const f32x4 (&acc)[MF][NF]) {
    #pragma unroll
    for (int mi = 0; mi < MF; ++mi) {
        #pragma unroll
        for (int ni = 0; ni < NF; ++ni) {
            const int gcol = n0 + brow_base + ni * 16 + lr;
            if (gcol < N) {
                const int grow0 = m0 + arow_base + mi * 16 + lg * 4;
                #pragma unroll
                for (int r = 0; r < 4; ++r) {
                    const float v = acc[mi][ni][r];
                    if constexpr (std::is_same<CT, float>::value)
                        C[(size_t)(grow0 + r) * ldc + gcol] = v;
                    else
                        C[(size_t)(grow0 + r) * ldc + gcol] = f2bf(v);
                }
            }
        }
    }
}

__device__ __forceinline__ int xcd_swizzle(int bid, int nwg) {
    const int q = nwg >> 3, r = nwg & 7;
    const int xcd = bid & 7, idx = bid >> 3;
    return (xcd < r ? xcd * (q + 1) : r * (q + 1) + (xcd - r) * q) + idx;
}

// ---------------------------------------------------------------------------
// Launch 1: W -> Wt (bf16 transpose) + x -> xb (bf16). 768 blocks.
// ---------------------------------------------------------------------------
__global__ __launch_bounds__(256) void prep_wx(const float* __restrict__ W,
                                               const float* __restrict__ x,
                                               unsigned short* __restrict__ Wt,
                                               unsigned short* __restrict__ xb) {
    const int bid = blockIdx.x, t = threadIdx.x;
    if (bid < 512) {
        __shared__ unsigned short tile[32][33];
        const int k0 = (bid & 31) * 32, n0 = (bid >> 5) * 32;
        const int c = t & 31, y = t >> 5;
        #pragma unroll
        for (int j = 0; j < 4; ++j)
            tile[y + j * 8][c] = f2bf(W[(size_t)(k0 + y + j * 8) * 512 + n0 + c]);
        __syncthreads();
        #pragma unroll
        for (int j = 0; j < 4; ++j)
            Wt[(size_t)(n0 + y + j * 8) * 1024 + k0 + c] = tile[c][y + j * 8];
    } else {
        const size_t base = (size_t)(bid - 512) * 2048 + (size_t)t * 8;
        const f32x4 v0 = *reinterpret_cast<const f32x4*>(x + base);
        const f32x4 v1 = *reinterpret_cast<const f32x4*>(x + base + 4);
        uint4 o;
        o.x = (unsigned)f2bf(v0.x) | ((unsigned)f2bf(v0.y) << 16);
        o.y = (unsigned)f2bf(v0.z) | ((unsigned)f2bf(v0.w) << 16);
        o.z = (unsigned)f2bf(v1.x) | ((unsigned)f2bf(v1.y) << 16);
        o.w = (unsigned)f2bf(v1.z) | ((unsigned)f2bf(v1.w) << 16);
        *reinterpret_cast<uint4*>(xb + base) = o;
    }
}

// ---------------------------------------------------------------------------
// Launch 2: GEMM1  C1[512,512] = xb @ Wt^T  (bf16 out). Tile 32x64, dbuf.
// 128 blocks, K=1024 -> 16 K-steps.
// ---------------------------------------------------------------------------
__global__ __launch_bounds__(256) void gemm1(const unsigned short* __restrict__ xb,
                                             const unsigned short* __restrict__ Wt,
                                             unsigned short* __restrict__ C1) {
    constexpr int MF = 1, NF = 2, BM = 32, BN = 64, M = 512, N = 512, K = 1024;
    constexpr int BUF = (BM + BN) * 128;
    __shared__ __align__(16) char lds[2 * BUF];

    const int bid = xcd_swizzle((int)blockIdx.x, 128);
    const int m0 = (bid & 15) * BM;        // nbM = 16
    const int n0 = (bid >> 4) * BN;

    const int tid = threadIdx.x, lane = tid & 63, wid = tid >> 6;
    const int wm = wid >> 1, wn = wid & 1;
    const int arow_base = wm * (16 * MF);
    const int brow_base = wn * (16 * NF);
    const int lr = lane & 15, lg = lane >> 4;

    f32x4 acc[MF][NF] = {};

    stage_lds<BM>(xb, K, m0, 0, M, lds, wid, lane);
    stage_lds<BN>(Wt, K, n0, 0, N, lds + BM * 128, wid, lane);
    __syncthreads();

    int cur = 0;
    for (int t = 0; t < K / 64; ++t) {
        const int kn = (t + 1) * 64;
        char* curb = lds + cur * BUF;
        char* nxtb = lds + (cur ^ 1) * BUF;
        if (t < K / 64 - 1) {
            stage_lds<BM>(xb, K, m0, kn, M, nxtb, wid, lane);
            stage_lds<BN>(Wt, K, n0, kn, N, nxtb + BM * 128, wid, lane);
        }
        compute_step<MF, NF>(curb, curb + BM * 128, arow_base, brow_base, lr, lg, acc);
        __syncthreads();
        cur ^= 1;
    }
    store_c<MF, NF>(C1, N, N, m0, n0, arow_base, brow_base, lr, lg, acc);
}

// ---------------------------------------------------------------------------
// Launch 3: GEMM2  out[512,20000] = C1 @ E^T  (f32 out). Tile 128x128, dbuf.
// A = C1 bf16 via global_load_lds; B = E f32 via T14 reg-stage + cvt.
// 628 blocks, K=512 -> 8 K-steps.
// ---------------------------------------------------------------------------
__global__ __launch_bounds__(256) void gemm2(const unsigned short* __restrict__ C1,
                                             const float* __restrict__ E,
                                             float* __restrict__ out) {
    constexpr int MF = 4, NF = 4, BM = 128, BN = 128;
    constexpr int M = 512, N = 20000, K = 512;
    constexpr int BUF = (BM + BN) * 128;
    __shared__ __align__(16) char lds[2 * BUF];     // 64 KiB

    const int bid = xcd_swizzle((int)blockIdx.x, (int)gridDim.x);
    const int m0 = (bid & 3) * BM;                  // nbM = 4 (m-fastest: 4 blocks share E panel)
    const int n0 = (bid >> 2) * BN;

    const int tid = threadIdx.x, lane = tid & 63, wid = tid >> 6;
    const int wm = wid >> 1, wn = wid & 1;
    const int arow_base = wm * (16 * MF);
    const int brow_base = wn * (16 * NF);
    const int lr = lane & 15, lg = lane >> 4;

    f32x4 acc[MF][NF] = {};
    f32x4 bregs[BN / 16];

    // prologue: tile 0
    stage_lds<BM>(C1, K, m0, 0, M, lds, wid, lane);
    stageB_load<BN>(E, K, n0, 0, N, bregs, tid);
    stageB_write<BN>(bregs, lds + BM * 128, tid);
    __syncthreads();

    int cur = 0;
    for (int t = 0; t < K / 64; ++t) {
        const int kn = (t + 1) * 64;
        char* curb = lds + cur * BUF;
        char* nxtb = lds + (cur ^ 1) * BUF;
        if (t < K / 64 - 1) {
            stageB_load<BN>(E, K, n0, kn, N, bregs, tid);   // issue early (T14)
            stage_lds<BM>(C1, K, m0, kn, M, nxtb, wid, lane);
        }
        compute_step<MF, NF>(curb, curb + BM * 128, arow_base, brow_base, lr, lg, acc);
        if (t < K / 64 - 1)
            stageB_write<BN>(bregs, nxtb + BM * 128, tid);  // write late
        __syncthreads();
        cur ^= 1;
    }
    store_c<MF, NF>(out, N, N, m0, n0, arow_base, brow_base, lr, lg, acc);
}

// ---------------------------------------------------------------------------

extern "C" void kernel_launch(void* const* d_in, const int* in_sizes, int n_in,
                              void* d_out, int out_size, void* d_ws, size_t ws_size,
                              hipStream_t stream) {
    const float* x = (const float*)d_in[0];     // [512,1024]
    const float* E = (const float*)d_in[1];     // [20000,512]
    const float* W = (const float*)d_in[2];     // [1024,512]
    float* out = (float*)d_out;                 // [512,20000]

    char* ws = (char*)d_ws;
    unsigned short* C1 = (unsigned short*)ws;                     // 512 KiB
    unsigned short* xb = (unsigned short*)(ws + 524288);          // 1 MiB
    unsigned short* Wt = (unsigned short*)(ws + 1572864);         // 1 MiB

    // 1) Wt + xb (bf16 prep)
    prep_wx<<<768, 256, 0, stream>>>(W, x, Wt, xb);

    // 2) C1 = xb @ Wt^T   (128 blocks)
    gemm1<<<128, 256, 0, stream>>>(xb, Wt, C1);

    // 3) out = C1 @ E^T   (157 N-tiles x 4 M-tiles = 628 blocks)
    gemm2<<<628, 256, 0, stream>>>(C1, E, out);
}

// Round 4
// 42.797 us; speedup vs baseline: 1.1226x; 1.1226x over previous
//
#include <hip/hip_runtime.h>
#include <type_traits>

typedef __attribute__((ext_vector_type(4))) float f32x4;
typedef __attribute__((ext_vector_type(8))) short s16x8;

__device__ __forceinline__ unsigned short f2bf(float f) {
    unsigned int u = __builtin_bit_cast(unsigned int, f);
    u += 0x7fffu + ((u >> 16) & 1u);           // round-to-nearest-even
    return (unsigned short)(u >> 16);
}

__device__ __forceinline__ void gload_lds16(const void* g, void* l) {
    __builtin_amdgcn_global_load_lds(
        (const __attribute__((address_space(1))) void*)g,
        (__attribute__((address_space(3))) void*)l, 16, 0, 0);
}

// ---------------------------------------------------------------------------
// LDS tile layout (bf16, 64 k-elems = 128 B per row):
//   byte(row, chunk) = row*128 + ((chunk ^ (row&7)) << 4)
// Staged via global_load_lds: linear LDS dest, pre-swizzled source chunk
// gchunk = (lane&7) ^ (lane>>3)  (valid since r0 is a multiple of 8).
// ---------------------------------------------------------------------------
template<int ROWS>
__device__ __forceinline__ void stage_lds(const unsigned short* __restrict__ src,
                                          int ld, int row0, int k0, int maxRowExcl,
                                          char* lds, int wid, int lane) {
    const int subrow = lane >> 3;            // 0..7
    const int gchunk = (lane & 7) ^ subrow;  // inverse swizzle on source
    #pragma unroll
    for (int p = 0; p < (ROWS + 31) / 32; ++p) {
        const int r0 = (p * 4 + wid) * 8;    // 8 rows / wave-call
        int gr = row0 + r0 + subrow;
        if (gr >= maxRowExcl) gr = maxRowExcl - 1;
        const char* g = (const char*)(src + (size_t)gr * ld + k0) + gchunk * 16;
        gload_lds16(g, lds + r0 * 128);      // wave-uniform base + lane*16
    }
}

// One BK=64 step: fragment reads + MFMA.
template<int MF, int NF>
__device__ __forceinline__ void compute_step(const char* As, const char* Bs,
                                             int arow_base, int brow_base,
                                             int lr, int lg, f32x4 (&acc)[MF][NF]) {
    #pragma unroll
    for (int kk = 0; kk < 2; ++kk) {
        s16x8 af[MF], bfr[NF];
        const int chunk = kk * 4 + lg;
        #pragma unroll
        for (int f = 0; f < MF; ++f) {
            const int row = arow_base + f * 16 + lr;
            af[f] = *reinterpret_cast<const s16x8*>(As + row * 128 + ((chunk ^ (row & 7)) << 4));
        }
        #pragma unroll
        for (int f = 0; f < NF; ++f) {
            const int row = brow_base + f * 16 + lr;
            bfr[f] = *reinterpret_cast<const s16x8*>(Bs + row * 128 + ((chunk ^ (row & 7)) << 4));
        }
        #pragma unroll
        for (int mi = 0; mi < MF; ++mi)
            #pragma unroll
            for (int ni = 0; ni < NF; ++ni)
                acc[mi][ni] = __builtin_amdgcn_mfma_f32_16x16x32_bf16(
                    af[mi], bfr[ni], acc[mi][ni], 0, 0, 0);
    }
}

// Epilogue: C/D layout col = lane&15, row = (lane>>4)*4 + reg   [m89]
template<int MF, int NF, typename CT>
__device__ __forceinline__ void store_c(CT* __restrict__ C, int ldc, int N,
                                        int m0, int n0, int arow_base, int brow_base,
                                        int lr, int lg, const f32x4 (&acc)[MF][NF]) {
    #pragma unroll
    for (int mi = 0; mi < MF; ++mi) {
        #pragma unroll
        for (int ni = 0; ni < NF; ++ni) {
            const int gcol = n0 + brow_base + ni * 16 + lr;
            if (gcol < N) {
                const int grow0 = m0 + arow_base + mi * 16 + lg * 4;
                #pragma unroll
                for (int r = 0; r < 4; ++r) {
                    const float v = acc[mi][ni][r];
                    if constexpr (std::is_same<CT, float>::value)
                        C[(size_t)(grow0 + r) * ldc + gcol] = v;
                    else
                        C[(size_t)(grow0 + r) * ldc + gcol] = f2bf(v);
                }
            }
        }
    }
}

__device__ __forceinline__ int xcd_swizzle(int bid, int nwg) {
    const int q = nwg >> 3, r = nwg & 7;
    const int xcd = bid & 7, idx = bid >> 3;
    return (xcd < r ? xcd * (q + 1) : r * (q + 1) + (xcd - r) * q) + idx;
}

// f32 -> bf16 convert, 2048 elems per block (256 thr x 8)
__device__ __forceinline__ void convert_chunk(const float* __restrict__ src,
                                              unsigned short* __restrict__ dst,
                                              int cblk, int t) {
    const size_t base = (size_t)cblk * 2048 + (size_t)t * 8;
    const f32x4 v0 = *reinterpret_cast<const f32x4*>(src + base);
    const f32x4 v1 = *reinterpret_cast<const f32x4*>(src + base + 4);
    uint4 o;
    o.x = (unsigned)f2bf(v0.x) | ((unsigned)f2bf(v0.y) << 16);
    o.y = (unsigned)f2bf(v0.z) | ((unsigned)f2bf(v0.w) << 16);
    o.z = (unsigned)f2bf(v1.x) | ((unsigned)f2bf(v1.y) << 16);
    o.w = (unsigned)f2bf(v1.z) | ((unsigned)f2bf(v1.w) << 16);
    *reinterpret_cast<uint4*>(dst + base) = o;
}

// ---------------------------------------------------------------------------
// K1: blocks [0,512) = W->Wt transpose; [512,768) = x->xb; [768,3768) = E part 1
// ---------------------------------------------------------------------------
__global__ __launch_bounds__(256) void prep_k1(const float* __restrict__ W,
                                               const float* __restrict__ x,
                                               const float* __restrict__ E,
                                               unsigned short* __restrict__ Wt,
                                               unsigned short* __restrict__ xb,
                                               unsigned short* __restrict__ Eb) {
    const int bid = blockIdx.x, t = threadIdx.x;
    if (bid < 512) {
        __shared__ unsigned short tile[32][33];
        const int k0 = (bid & 31) * 32, n0 = (bid >> 5) * 32;
        const int c = t & 31, y = t >> 5;
        #pragma unroll
        for (int j = 0; j < 4; ++j)
            tile[y + j * 8][c] = f2bf(W[(size_t)(k0 + y + j * 8) * 512 + n0 + c]);
        __syncthreads();
        #pragma unroll
        for (int j = 0; j < 4; ++j)
            Wt[(size_t)(n0 + y + j * 8) * 1024 + k0 + c] = tile[c][y + j * 8];
    } else if (bid < 768) {
        convert_chunk(x, xb, bid - 512, t);
    } else {
        convert_chunk(E, Eb, bid - 768, t);
    }
}

// ---------------------------------------------------------------------------
// K2: blocks [0,128) = GEMM1 (C1 = xb @ Wt^T, 32x64 tiles, dbuf);
//     blocks [128,2128) = E convert part 2 (blocks 3000..4999)
// ---------------------------------------------------------------------------
__global__ __launch_bounds__(256) void gemm1_k2(const unsigned short* __restrict__ xb,
                                                const unsigned short* __restrict__ Wt,
                                                unsigned short* __restrict__ C1,
                                                const float* __restrict__ E,
                                                unsigned short* __restrict__ Eb) {
    constexpr int MF = 1, NF = 2, BM = 32, BN = 64, M = 512, N = 512, K = 1024;
    constexpr int BUF = (BM + BN) * 128;
    __shared__ __align__(16) char lds[2 * BUF];

    if (blockIdx.x >= 128) {
        convert_chunk(E, Eb, 3000 + (int)blockIdx.x - 128, (int)threadIdx.x);
        return;
    }

    const int bid = xcd_swizzle((int)blockIdx.x, 128);
    const int m0 = (bid & 15) * BM;        // nbM = 16
    const int n0 = (bid >> 4) * BN;

    const int tid = threadIdx.x, lane = tid & 63, wid = tid >> 6;
    const int wm = wid >> 1, wn = wid & 1;
    const int arow_base = wm * (16 * MF);
    const int brow_base = wn * (16 * NF);
    const int lr = lane & 15, lg = lane >> 4;

    f32x4 acc[MF][NF] = {};

    stage_lds<BM>(xb, K, m0, 0, M, lds, wid, lane);
    stage_lds<BN>(Wt, K, n0, 0, N, lds + BM * 128, wid, lane);
    __syncthreads();

    int cur = 0;
    for (int t = 0; t < K / 64; ++t) {
        char* curb = lds + cur * BUF;
        char* nxtb = lds + (cur ^ 1) * BUF;
        if (t < K / 64 - 1) {
            const int kn = (t + 1) * 64;
            stage_lds<BM>(xb, K, m0, kn, M, nxtb, wid, lane);
            stage_lds<BN>(Wt, K, n0, kn, N, nxtb + BM * 128, wid, lane);
        }
        compute_step<MF, NF>(curb, curb + BM * 128, arow_base, brow_base, lr, lg, acc);
        __syncthreads();
        cur ^= 1;
    }
    store_c<MF, NF>(C1, N, N, m0, n0, arow_base, brow_base, lr, lg, acc);
}

// ---------------------------------------------------------------------------
// K3: GEMM2  out[512,20000] = C1 @ Eb^T  (f32 out). Tile 128x128, all-bf16
// gload_lds staging, dbuf prefetch. 628 blocks, K=512 -> 8 K-steps.
// ---------------------------------------------------------------------------
__global__ __launch_bounds__(256) void gemm2(const unsigned short* __restrict__ C1,
                                             const unsigned short* __restrict__ Eb,
                                             float* __restrict__ out) {
    constexpr int MF = 4, NF = 4, BM = 128, BN = 128;
    constexpr int M = 512, N = 20000, K = 512;
    constexpr int BUF = (BM + BN) * 128;
    __shared__ __align__(16) char lds[2 * BUF];     // 64 KiB -> 2 blocks/CU

    const int bid = xcd_swizzle((int)blockIdx.x, (int)gridDim.x);
    const int m0 = (bid & 3) * BM;                  // 4 consecutive bids share E panel
    const int n0 = (bid >> 2) * BN;

    const int tid = threadIdx.x, lane = tid & 63, wid = tid >> 6;
    const int wm = wid >> 1, wn = wid & 1;
    const int arow_base = wm * (16 * MF);
    const int brow_base = wn * (16 * NF);
    const int lr = lane & 15, lg = lane >> 4;

    f32x4 acc[MF][NF] = {};

    stage_lds<BM>(C1, K, m0, 0, M, lds, wid, lane);
    stage_lds<BN>(Eb, K, n0, 0, N, lds + BM * 128, wid, lane);
    __syncthreads();

    int cur = 0;
    for (int t = 0; t < K / 64; ++t) {
        char* curb = lds + cur * BUF;
        char* nxtb = lds + (cur ^ 1) * BUF;
        if (t < K / 64 - 1) {
            const int kn = (t + 1) * 64;
            stage_lds<BM>(C1, K, m0, kn, M, nxtb, wid, lane);      // prefetch next
            stage_lds<BN>(Eb, K, n0, kn, N, nxtb + BM * 128, wid, lane);
        }
        compute_step<MF, NF>(curb, curb + BM * 128, arow_base, brow_base, lr, lg, acc);
        __syncthreads();    // vmcnt(0) drain covered by the compute above
        cur ^= 1;
    }
    store_c<MF, NF>(out, N, N, m0, n0, arow_base, brow_base, lr, lg, acc);
}

// ---------------------------------------------------------------------------

extern "C" void kernel_launch(void* const* d_in, const int* in_sizes, int n_in,
                              void* d_out, int out_size, void* d_ws, size_t ws_size,
                              hipStream_t stream) {
    const float* x = (const float*)d_in[0];     // [512,1024]
    const float* E = (const float*)d_in[1];     // [20000,512]
    const float* W = (const float*)d_in[2];     // [1024,512]
    float* out = (float*)d_out;                 // [512,20000]

    char* ws = (char*)d_ws;
    unsigned short* C1 = (unsigned short*)ws;                     // 512 KiB
    unsigned short* xb = (unsigned short*)(ws + 524288);          // 1 MiB
    unsigned short* Wt = (unsigned short*)(ws + 1572864);         // 1 MiB
    unsigned short* Eb = (unsigned short*)(ws + 2621440);         // 20.48 MB

    // K1: Wt + xb + E-convert part 1 (3000 of 5000 chunks)
    prep_k1<<<3768, 256, 0, stream>>>(W, x, E, Wt, xb, Eb);

    // K2: gemm1 (128 blocks) + E-convert part 2 (2000 chunks)
    gemm1_k2<<<2128, 256, 0, stream>>>(xb, Wt, C1, E, Eb);

    // K3: gemm2, 157 N-tiles x 4 M-tiles = 628 blocks
    gemm2<<<628, 256, 0, stream>>>(C1, Eb, out);
}

// Round 5
// 41.317 us; speedup vs baseline: 1.1628x; 1.0358x over previous
//
#include <hip/hip_runtime.h>
#include <type_traits>

typedef __attribute__((ext_vector_type(4))) float f32x4;
typedef __attribute__((ext_vector_type(8))) short s16x8;

__device__ __forceinline__ unsigned short f2bf(float f) {
    unsigned int u = __builtin_bit_cast(unsigned int, f);
    u += 0x7fffu + ((u >> 16) & 1u);           // round-to-nearest-even
    return (unsigned short)(u >> 16);
}

__device__ __forceinline__ void gload_lds16(const void* g, void* l) {
    __builtin_amdgcn_global_load_lds(
        (const __attribute__((address_space(1))) void*)g,
        (__attribute__((address_space(3))) void*)l, 16, 0, 0);
}

// ---------------------------------------------------------------------------
// LDS tile layout (bf16, 64 k-elems = 128 B per row):
//   byte(row, chunk) = row*128 + ((chunk ^ (row&7)) << 4)
// Staged via global_load_lds: linear LDS dest, pre-swizzled source chunk
// gchunk = (lane&7) ^ (lane>>3)  (valid since r0 is a multiple of 8).
// ---------------------------------------------------------------------------
template<int ROWS>
__device__ __forceinline__ void stage_lds(const unsigned short* __restrict__ src,
                                          int ld, int row0, int k0, int maxRowExcl,
                                          char* lds, int wid, int lane) {
    const int subrow = lane >> 3;            // 0..7
    const int gchunk = (lane & 7) ^ subrow;  // inverse swizzle on source
    #pragma unroll
    for (int p = 0; p < (ROWS + 31) / 32; ++p) {
        const int r0 = (p * 4 + wid) * 8;    // 8 rows / wave-call
        int gr = row0 + r0 + subrow;
        if (gr >= maxRowExcl) gr = maxRowExcl - 1;
        const char* g = (const char*)(src + (size_t)gr * ld + k0) + gchunk * 16;
        gload_lds16(g, lds + r0 * 128);      // wave-uniform base + lane*16
    }
}

// Fragment reads for one BK=64 tile (both kk halves), then MFMA separately.
template<int MF, int NF>
__device__ __forceinline__ void read_frags(const char* As, const char* Bs,
                                           int arow_base, int brow_base,
                                           int lr, int lg,
                                           s16x8 (&af)[2][MF], s16x8 (&bfr)[2][NF]) {
    #pragma unroll
    for (int kk = 0; kk < 2; ++kk) {
        const int chunk = kk * 4 + lg;
        #pragma unroll
        for (int f = 0; f < MF; ++f) {
            const int row = arow_base + f * 16 + lr;
            af[kk][f] = *reinterpret_cast<const s16x8*>(As + row * 128 + ((chunk ^ (row & 7)) << 4));
        }
        #pragma unroll
        for (int f = 0; f < NF; ++f) {
            const int row = brow_base + f * 16 + lr;
            bfr[kk][f] = *reinterpret_cast<const s16x8*>(Bs + row * 128 + ((chunk ^ (row & 7)) << 4));
        }
    }
}

template<int MF, int NF>
__device__ __forceinline__ void mfma_all(const s16x8 (&af)[2][MF], const s16x8 (&bfr)[2][NF],
                                         f32x4 (&acc)[MF][NF]) {
    #pragma unroll
    for (int kk = 0; kk < 2; ++kk)
        #pragma unroll
        for (int mi = 0; mi < MF; ++mi)
            #pragma unroll
            for (int ni = 0; ni < NF; ++ni)
                acc[mi][ni] = __builtin_amdgcn_mfma_f32_16x16x32_bf16(
                    af[kk][mi], bfr[kk][ni], acc[mi][ni], 0, 0, 0);
}

// One BK=64 step (read + MFMA fused) — used by gemm1 and gemm2's last tile.
template<int MF, int NF>
__device__ __forceinline__ void compute_step(const char* As, const char* Bs,
                                             int arow_base, int brow_base,
                                             int lr, int lg, f32x4 (&acc)[MF][NF]) {
    s16x8 af[2][MF], bfr[2][NF];
    read_frags<MF, NF>(As, Bs, arow_base, brow_base, lr, lg, af, bfr);
    mfma_all<MF, NF>(af, bfr, acc);
}

__device__ __forceinline__ int xcd_swizzle(int bid, int nwg) {
    const int q = nwg >> 3, r = nwg & 7;
    const int xcd = bid & 7, idx = bid >> 3;
    return (xcd < r ? xcd * (q + 1) : r * (q + 1) + (xcd - r) * q) + idx;
}

// f32 -> bf16 convert, 2048 elems per block (256 thr x 8)
__device__ __forceinline__ void convert_chunk(const float* __restrict__ src,
                                              unsigned short* __restrict__ dst,
                                              int cblk, int t) {
    const size_t base = (size_t)cblk * 2048 + (size_t)t * 8;
    const f32x4 v0 = *reinterpret_cast<const f32x4*>(src + base);
    const f32x4 v1 = *reinterpret_cast<const f32x4*>(src + base + 4);
    uint4 o;
    o.x = (unsigned)f2bf(v0.x) | ((unsigned)f2bf(v0.y) << 16);
    o.y = (unsigned)f2bf(v0.z) | ((unsigned)f2bf(v0.w) << 16);
    o.z = (unsigned)f2bf(v1.x) | ((unsigned)f2bf(v1.y) << 16);
    o.w = (unsigned)f2bf(v1.z) | ((unsigned)f2bf(v1.w) << 16);
    *reinterpret_cast<uint4*>(dst + base) = o;
}

// ---------------------------------------------------------------------------
// K1: [0,512) W->Wt transpose; [512,768) x->xb; [768,3968) E convert part 1,
// XCD-targeted: block's XCD x = bid&7 converts chunks x*640 + l (l<400) so Eb
// lands in the L2 of the XCD whose gemm2 blocks will read it.
// ---------------------------------------------------------------------------
__global__ __launch_bounds__(256) void prep_k1(const float* __restrict__ W,
                                               const float* __restrict__ x,
                                               const float* __restrict__ E,
                                               unsigned short* __restrict__ Wt,
                                               unsigned short* __restrict__ xb,
                                               unsigned short* __restrict__ Eb) {
    const int bid = blockIdx.x, t = threadIdx.x;
    if (bid < 512) {
        __shared__ unsigned short tile[32][33];
        const int k0 = (bid & 31) * 32, n0 = (bid >> 5) * 32;
        const int c = t & 31, y = t >> 5;
        #pragma unroll
        for (int j = 0; j < 4; ++j)
            tile[y + j * 8][c] = f2bf(W[(size_t)(k0 + y + j * 8) * 512 + n0 + c]);
        __syncthreads();
        #pragma unroll
        for (int j = 0; j < 4; ++j)
            Wt[(size_t)(n0 + y + j * 8) * 1024 + k0 + c] = tile[c][y + j * 8];
    } else if (bid < 768) {
        convert_chunk(x, xb, bid - 512, t);
    } else {
        const int x7 = bid & 7, l = (bid - 768) >> 3;       // l in [0,400)
        convert_chunk(E, Eb, x7 * 640 + l, t);              // always < 5000
    }
}

// ---------------------------------------------------------------------------
// K2: [0,128) GEMM1 (C1 = xb @ Wt^T, 32x64 tiles, dbuf);
//     [128,2048) E convert part 2: chunk = (bid&7)*640 + 400 + l2, skip >=5000
// ---------------------------------------------------------------------------
__global__ __launch_bounds__(256) void gemm1_k2(const unsigned short* __restrict__ xb,
                                                const unsigned short* __restrict__ Wt,
                                                unsigned short* __restrict__ C1,
                                                const float* __restrict__ E,
                                                unsigned short* __restrict__ Eb) {
    constexpr int MF = 1, NF = 2, BM = 32, BN = 64, M = 512, N = 512, K = 1024;
    constexpr int BUF = (BM + BN) * 128;
    __shared__ __align__(16) char lds[2 * BUF];

    if (blockIdx.x >= 128) {
        const int x7 = (int)blockIdx.x & 7, l2 = ((int)blockIdx.x - 128) >> 3; // l2 in [0,240)
        const int chunk = x7 * 640 + 400 + l2;
        if (chunk < 5000) convert_chunk(E, Eb, chunk, (int)threadIdx.x);
        return;
    }

    const int bid = xcd_swizzle((int)blockIdx.x, 128);
    const int m0 = (bid & 15) * BM;        // nbM = 16
    const int n0 = (bid >> 4) * BN;

    const int tid = threadIdx.x, lane = tid & 63, wid = tid >> 6;
    const int wm = wid >> 1, wn = wid & 1;
    const int arow_base = wm * (16 * MF);
    const int brow_base = wn * (16 * NF);
    const int lr = lane & 15, lg = lane >> 4;

    f32x4 acc[MF][NF] = {};

    stage_lds<BM>(xb, K, m0, 0, M, lds, wid, lane);
    stage_lds<BN>(Wt, K, n0, 0, N, lds + BM * 128, wid, lane);
    __syncthreads();

    int cur = 0;
    for (int t = 0; t < K / 64; ++t) {
        char* curb = lds + cur * BUF;
        char* nxtb = lds + (cur ^ 1) * BUF;
        if (t < K / 64 - 1) {
            const int kn = (t + 1) * 64;
            stage_lds<BM>(xb, K, m0, kn, M, nxtb, wid, lane);
            stage_lds<BN>(Wt, K, n0, kn, N, nxtb + BM * 128, wid, lane);
        }
        compute_step<MF, NF>(curb, curb + BM * 128, arow_base, brow_base, lr, lg, acc);
        __syncthreads();
        cur ^= 1;
    }
    // store C1 (cached — gemm2 reads it right away)
    #pragma unroll
    for (int mi = 0; mi < MF; ++mi)
        #pragma unroll
        for (int ni = 0; ni < NF; ++ni) {
            const int gcol = n0 + brow_base + ni * 16 + lr;
            const int grow0 = m0 + arow_base + mi * 16 + lg * 4;
            #pragma unroll
            for (int r = 0; r < 4; ++r)
                C1[(size_t)(grow0 + r) * N + gcol] = f2bf(acc[mi][ni][r]);
        }
}

// ---------------------------------------------------------------------------
// K3: GEMM2  out[512,20000] = C1 @ Eb^T (f32). Tile 128x160 (20000 = 125*160,
// no N edge), grid 512 (500 real, 12 dummies), 2 blocks/CU.
// Counted-vmcnt 2-buffer pipeline (T4): never drain vmcnt to 0 in the loop.
// Per wave per tile: 9 global_load_lds (A:4, B:5).
// ---------------------------------------------------------------------------
__global__ __launch_bounds__(256) void gemm2(const unsigned short* __restrict__ C1,
                                             const unsigned short* __restrict__ Eb,
                                             float* __restrict__ out) {
    constexpr int MF = 4, NF = 5, BM = 128, BN = 160;
    constexpr int M = 512, N = 20000, K = 512, NSTEP = K / 64;
    constexpr int BUF = (BM + BN) * 128;                // 36864 B
    __shared__ __align__(16) char lds[2 * BUF];         // 72 KiB -> 2 blocks/CU

    // chunked XCD swizzle, cpx = 64: XCD x owns n-tiles [16x, 16x+16)
    const int nb = ((int)blockIdx.x & 7) * 64 + ((int)blockIdx.x >> 3);
    if (nb >= 500) return;
    const int m0 = (nb & 3) * BM;                       // 4 m-blocks share Eb panel
    const int n0 = (nb >> 2) * BN;

    const int tid = threadIdx.x, lane = tid & 63, wid = tid >> 6;
    const int wm = wid >> 1, wn = wid & 1;
    const int arow_base = wm * (16 * MF);               // 0 / 64
    const int brow_base = wn * (16 * NF);               // 0 / 80
    const int lr = lane & 15, lg = lane >> 4;

    f32x4 acc[MF][NF] = {};

    // prologue: issue tiles 0 and 1 (9 loads each per wave)
    stage_lds<BM>(C1, K, m0, 0, M, lds, wid, lane);
    stage_lds<BN>(Eb, K, n0, 0, N, lds + BM * 128, wid, lane);
    stage_lds<BM>(C1, K, m0, 64, M, lds + BUF, wid, lane);
    stage_lds<BN>(Eb, K, n0, 64, N, lds + BUF + BM * 128, wid, lane);

    for (int t = 0; t < NSTEP - 1; ++t) {
        char* cur = lds + (t & 1) * BUF;
        // tile t's 9 loads done; tile t+1's 9 still in flight
        asm volatile("s_waitcnt vmcnt(9)" ::: "memory");
        __builtin_amdgcn_s_barrier();

        s16x8 af[2][MF], bfr[2][NF];
        read_frags<MF, NF>(cur, cur + BM * 128, arow_base, brow_base, lr, lg, af, bfr);
        asm volatile("s_waitcnt lgkmcnt(0)" ::: "memory");
        __builtin_amdgcn_sched_barrier(0);              // rule 18
        __builtin_amdgcn_s_barrier();                   // all waves done reading cur

        if (t + 2 < NSTEP) {                            // overwrite cur with tile t+2
            const int kn = (t + 2) * 64;
            stage_lds<BM>(C1, K, m0, kn, M, cur, wid, lane);
            stage_lds<BN>(Eb, K, n0, kn, N, cur + BM * 128, wid, lane);
        }
        mfma_all<MF, NF>(af, bfr, acc);                 // hides t+1/t+2 latency
    }
    // last tile: full drain
    {
        char* cur = lds + ((NSTEP - 1) & 1) * BUF;
        asm volatile("s_waitcnt vmcnt(0)" ::: "memory");
        __builtin_amdgcn_s_barrier();
        compute_step<MF, NF>(cur, cur + BM * 128, arow_base, brow_base, lr, lg, acc);
    }

    // epilogue: nontemporal stores (keep Eb/C1 L2-resident)
    #pragma unroll
    for (int mi = 0; mi < MF; ++mi)
        #pragma unroll
        for (int ni = 0; ni < NF; ++ni) {
            const int gcol = n0 + brow_base + ni * 16 + lr;
            const int grow0 = m0 + arow_base + mi * 16 + lg * 4;
            #pragma unroll
            for (int r = 0; r < 4; ++r)
                __builtin_nontemporal_store(acc[mi][ni][r],
                    &out[(size_t)(grow0 + r) * N + gcol]);
        }
}

// ---------------------------------------------------------------------------

extern "C" void kernel_launch(void* const* d_in, const int* in_sizes, int n_in,
                              void* d_out, int out_size, void* d_ws, size_t ws_size,
                              hipStream_t stream) {
    const float* x = (const float*)d_in[0];     // [512,1024]
    const float* E = (const float*)d_in[1];     // [20000,512]
    const float* W = (const float*)d_in[2];     // [1024,512]
    float* out = (float*)d_out;                 // [512,20000]

    char* ws = (char*)d_ws;
    unsigned short* C1 = (unsigned short*)ws;                     // 512 KiB
    unsigned short* xb = (unsigned short*)(ws + 524288);          // 1 MiB
    unsigned short* Wt = (unsigned short*)(ws + 1572864);         // 1 MiB
    unsigned short* Eb = (unsigned short*)(ws + 2621440);         // 20.48 MB

    // K1: Wt + xb + E-convert part 1 (3200 chunks, XCD-targeted)
    prep_k1<<<3968, 256, 0, stream>>>(W, x, E, Wt, xb, Eb);

    // K2: gemm1 (128 blocks) + E-convert part 2 (1920 chunks)
    gemm1_k2<<<2048, 256, 0, stream>>>(xb, Wt, C1, E, Eb);

    // K3: gemm2, 125 n-tiles x 4 m-tiles = 500 blocks (+12 dummies)
    gemm2<<<512, 256, 0, stream>>>(C1, Eb, out);
}